// Round 8
// baseline (208.225 us; speedup 1.0000x reference)
//
#include <hip/hip_runtime.h>
#include <hip/hip_bf16.h>

// MultiHead attention, MI355X/gfx950. fp32 in/out, bf16 MFMA internals.
// B=2, T=2048, C=1024, H=16, D=64.
// Round 8: split-K attention. No-max softmax makes attention LINEAR over the
// key range: partial (O_num, l) from disjoint K-chunks combine by addition.
// Each (b,h,64-row Q-tile) -> 2 chunks of <=16 k-tiles; grid 2048 (8/CU
// queued, 4 resident -> refill kills the tail; round 7's 56us was one
// 32-stage serial chain on a mostly idle machine). Combine kernel divides.
//
// ws layout (bf16 elems):
//   xb  [4096][1024]   @ 0          (x bf16; dead after qkv_gemm -> reused as Op0)
//   wt  [3072][1024]   @ 4194304    (Wq/Wk/Wv fused, transposed)
//   wot [1024][1024]   @ 7340032    (Wo transposed)
//   qkv Q,K:[h][b*2048+t][d] Vt:[h][b][d][t] @ 8388608  (Q pre-scaled 1/32)
//   att [4096][1024]   @ 20971520
//   Op1 [4096][1024]   @ 25165824   (chunk-1 partial numerator, bf16)
//   lp  [2][16][4096]  @ 29360128   (fp32 partial denominators, 512KB)
// peak ws = 59.2 MB

typedef __hip_bfloat16 bf16;
typedef __bf16 v8bf __attribute__((ext_vector_type(8)));
typedef float  v4f  __attribute__((ext_vector_type(4)));
typedef unsigned long long u64;
typedef unsigned int u32;

#define MFMA16(a, b, c) __builtin_amdgcn_mfma_f32_16x16x32_bf16((a), (b), (c), 0, 0, 0)

__device__ __forceinline__ bf16 f2b(float x) { return __float2bfloat16(x); }
__device__ __forceinline__ __bf16 f2braw(float x) {
  bf16 t = __float2bfloat16(x);
  return *reinterpret_cast<__bf16*>(&t);
}
__device__ __forceinline__ unsigned short f2bu(float x) {
  bf16 t = __float2bfloat16(x);
  return *reinterpret_cast<unsigned short*>(&t);
}

// async global->LDS, 16B per lane; LDS dest = wave-uniform base + lane*16.
__device__ __forceinline__ void load16_lds(const bf16* gptr, const bf16* lptr) {
  __builtin_amdgcn_global_load_lds(
      (const __attribute__((address_space(1))) u32*)gptr,
      (__attribute__((address_space(3))) u32*)lptr, 16, 0, 0);
}

// ---------------------------------------------------------------------------
// Fused prep: [0,2048) cvt_x | [2048,5120) Wq/Wk/Wv transpose | [5120,6144) Wo.
// ---------------------------------------------------------------------------
__global__ __launch_bounds__(256) void prep_kernel(
    const float* __restrict__ x,
    const float* __restrict__ Wq, const float* __restrict__ Wk,
    const float* __restrict__ Wv, const float* __restrict__ Wo,
    bf16* __restrict__ xb, bf16* __restrict__ wt, bf16* __restrict__ wot)
{
  __shared__ float Lt[32][33];
  const int bid = blockIdx.x, tid = threadIdx.x;

  if (bid < 2048) {                        // x fp32 -> bf16
    size_t i = ((size_t)bid * 256 + tid) * 8;
    float4 f0 = *(const float4*)(x + i);
    float4 f1 = *(const float4*)(x + i + 4);
    v8bf v;
    v[0] = f2braw(f0.x); v[1] = f2braw(f0.y); v[2] = f2braw(f0.z); v[3] = f2braw(f0.w);
    v[4] = f2braw(f1.x); v[5] = f2braw(f1.y); v[6] = f2braw(f1.z); v[7] = f2braw(f1.w);
    *(v8bf*)(xb + i) = v;
    return;
  }
  const int tx = tid & 31, ty = tid >> 5;
  if (bid < 5120) {                        // Wq/Wk/Wv [h][1024][64] -> wt [z][64][1024]
    const int idx = bid - 2048;
    const int z = idx >> 6, rem = idx & 63;
    const int p = z >> 4, h = z & 15;
    const float* ib = ((p == 0) ? Wq : (p == 1) ? Wk : Wv) + (size_t)h * 65536;
    bf16* ob = wt + (size_t)z * 65536;
    const int j0 = (rem & 1) * 32, i0 = (rem >> 1) * 32;
    #pragma unroll
    for (int r = 0; r < 4; ++r)
      Lt[ty + 8 * r][tx] = ib[(size_t)(i0 + ty + 8 * r) * 64 + j0 + tx];
    __syncthreads();
    #pragma unroll
    for (int r = 0; r < 4; ++r)
      ob[(size_t)(j0 + ty + 8 * r) * 1024 + i0 + tx] = f2b(Lt[tx][ty + 8 * r]);
  } else {                                 // Wo [1024][1024] -> wot transposed
    const int idx = bid - 5120;
    const int j0 = (idx & 31) * 32, i0 = (idx >> 5) * 32;
    #pragma unroll
    for (int r = 0; r < 4; ++r)
      Lt[ty + 8 * r][tx] = Wo[(size_t)(i0 + ty + 8 * r) * 1024 + j0 + tx];
    __syncthreads();
    #pragma unroll
    for (int r = 0; r < 4; ++r)
      wot[(size_t)(j0 + ty + 8 * r) * 1024 + i0 + tx] = f2b(Lt[tx][ty + 8 * r]);
  }
}

// ---------------------------------------------------------------------------
// Kernel 1: fused QKV GEMM, M=4096 x N=3072, K=1024. 128x128 tile, BK=32,
// double-buffered LDS, one barrier per k-step; next-tile loads issued
// BEFORE current fragment reads. grid (32 mt, 24 nt).
// ---------------------------------------------------------------------------
__global__ __launch_bounds__(256) void qkv_gemm_kernel(
    const bf16* __restrict__ xb, const bf16* __restrict__ wt,
    bf16* __restrict__ qkv)
{
  __shared__ __align__(16) bf16 Ash[2][128][32];
  __shared__ __align__(16) bf16 Bsh[2][128][32];

  const int mt = blockIdx.x, nt = blockIdx.y;
  const int tid = threadIdx.x, w = tid >> 6, lane = tid & 63;
  const int ln = lane & 15, quad = lane >> 4;
  const int wm = w >> 1, wn = w & 1;
  const int m0 = mt * 128, n0 = nt * 128;

  const v4f vzero = {0.f, 0.f, 0.f, 0.f};
  v4f acc[4][4];
  #pragma unroll
  for (int mf = 0; mf < 4; ++mf)
    #pragma unroll
    for (int nf = 0; nf < 4; ++nf) acc[mf][nf] = vzero;

  const int srow = lane >> 2, sseg = (lane & 3) * 8;
  const bf16* ga = xb + (size_t)(m0 + 32 * w + srow) * 1024 + sseg;
  const bf16* gb = wt + (size_t)(n0 + 32 * w + srow) * 1024 + sseg;

  {
    load16_lds(ga,             &Ash[0][32 * w][0]);
    load16_lds(ga + 16 * 1024, &Ash[0][32 * w + 16][0]);
    load16_lds(gb,             &Bsh[0][32 * w][0]);
    load16_lds(gb + 16 * 1024, &Bsh[0][32 * w + 16][0]);
  }

  for (int kt = 0; kt < 32; ++kt) {
    const int buf = kt & 1;
    __syncthreads();                       // publishes buf (drains loads)

    if (kt < 31) {                         // stage kt+1 first (async, other buf)
      const int k0 = (kt + 1) * 32, nb = buf ^ 1;
      load16_lds(ga + k0,             &Ash[nb][32 * w][0]);
      load16_lds(ga + 16 * 1024 + k0, &Ash[nb][32 * w + 16][0]);
      load16_lds(gb + k0,             &Bsh[nb][32 * w][0]);
      load16_lds(gb + 16 * 1024 + k0, &Bsh[nb][32 * w + 16][0]);
    }

    v8bf af[4], bfv[4];
    #pragma unroll
    for (int mf = 0; mf < 4; ++mf)
      af[mf] = *(const v8bf*)&Ash[buf][wm * 64 + mf * 16 + ln][quad * 8];
    #pragma unroll
    for (int nf = 0; nf < 4; ++nf)
      bfv[nf] = *(const v8bf*)&Bsh[buf][wn * 64 + nf * 16 + ln][quad * 8];

    #pragma unroll
    for (int mf = 0; mf < 4; ++mf)
      #pragma unroll
      for (int nf = 0; nf < 4; ++nf)
        acc[mf][nf] = MFMA16(af[mf], bfv[nf], acc[mf][nf]);
  }

  const int jcol0 = n0 + wn * 64;
  const int p = jcol0 >> 10;
  const int h = (jcol0 >> 6) & 15;
  const float scale = (p == 0) ? 0.03125f : 1.0f;

  if (p < 2) {                               // Q, K: [h][m][d]
    bf16* base = qkv + (size_t)p * 4194304 + (size_t)h * 262144;
    #pragma unroll
    for (int mf = 0; mf < 4; ++mf)
      #pragma unroll
      for (int nf = 0; nf < 4; ++nf) {
        int d = nf * 16 + ln;
        #pragma unroll
        for (int r = 0; r < 4; ++r) {
          int m = m0 + wm * 64 + mf * 16 + quad * 4 + r;
          base[(size_t)m * 64 + d] = f2b(acc[mf][nf][r] * scale);
        }
      }
  } else {                                   // V transposed: [h][b][d][t]
    bf16* vb = qkv + (size_t)2 * 4194304 + (size_t)h * 262144;
    #pragma unroll
    for (int mf = 0; mf < 4; ++mf) {
      int mrow = m0 + wm * 64 + mf * 16 + quad * 4;
      int bi = mrow >> 11, t0 = mrow & 2047;
      #pragma unroll
      for (int nf = 0; nf < 4; ++nf) {
        int d = nf * 16 + ln;
        u64 pk = (u64)f2bu(acc[mf][nf][0]) |
                 ((u64)f2bu(acc[mf][nf][1]) << 16) |
                 ((u64)f2bu(acc[mf][nf][2]) << 32) |
                 ((u64)f2bu(acc[mf][nf][3]) << 48);
        *(u64*)(vb + (size_t)bi * 131072 + (size_t)d * 2048 + t0) = pk;
      }
    }
  }
}

// ---------------------------------------------------------------------------
// Kernel 2: split-K causal flash attention. Block = 2 waves x 32 Q-rows.
// fid bits: 0-4 mtraw | 5 chunk | 6-10 grp(b,h); mt flipped on bit 9.
// Chunk 0: k-tiles [0, c0), chunk 1: [c0, mt+1), c0 = (mt+2)>>1 (<=16 each).
// Partials: Op[chunk] = un-normalized numerator (bf16), lp[chunk] = row sums
// (fp32, via MFMA with B=ones). Double-buffered K/Vt tiles, one barrier per
// k-tile, next-tile loads issued before current fragment reads.
// ---------------------------------------------------------------------------
__global__ __launch_bounds__(128) void attn_kernel(
    const bf16* __restrict__ qkv, bf16* __restrict__ Op0,
    bf16* __restrict__ Op1, float* __restrict__ lp)
{
  __shared__ __align__(16) bf16 Ksh[2][2][64][32];   // [buf][d-seg][t'][32]
  __shared__ __align__(16) bf16 Vsh[2][2][64][32];   // [buf][t-seg][d][32]
  __shared__ __align__(16) __bf16 Psh[2][16][72];

  const int fid = blockIdx.x;                        // 0..2047
  const int mtraw = fid & 31;
  const int chunk = (fid >> 5) & 1;
  const int grp = (fid >> 6) & 31;
  const int mt = ((fid >> 9) & 1) ? (31 - mtraw) : mtraw;
  const int b = grp >> 4, h = grp & 15;
  const int row0 = mt * 64;

  const int ntile = mt + 1;
  const int c0 = (ntile + 1) >> 1;                   // chunk-0 tile count
  const int kb_lo = chunk ? c0 : 0;
  const int kb_hi = chunk ? ntile : c0;              // exclusive

  const int tid = threadIdx.x, w = tid >> 6, lane = tid & 63;
  const int ln = lane & 15, quad = lane >> 4;

  const bf16* qbase  = qkv + (size_t)h * 262144 + (size_t)b * 131072;
  const bf16* kbase  = qbase + 4194304;
  const bf16* vtbase = qbase + 8388608;              // [d][t], d-stride 2048

  const int wrow = row0 + w * 32;
  v8bf aq[2][2];
  #pragma unroll
  for (int mc = 0; mc < 2; ++mc)
    #pragma unroll
    for (int ks = 0; ks < 2; ++ks)
      aq[mc][ks] = *(const v8bf*)(qbase +
          (size_t)(wrow + mc * 16 + ln) * 64 + ks * 32 + quad * 8);

  v8bf vone;
  {
    unsigned short u = 0x3F80;
    __bf16 one_e = *reinterpret_cast<__bf16*>(&u);
    #pragma unroll
    for (int j = 0; j < 8; ++j) vone[j] = one_e;
  }

  const v4f vzero = {0.f, 0.f, 0.f, 0.f};
  v4f o[2][4], lacc[2];
  #pragma unroll
  for (int mc = 0; mc < 2; ++mc) {
    lacc[mc] = vzero;
    #pragma unroll
    for (int n = 0; n < 4; ++n) o[mc][n] = vzero;
  }

  const float NEG = -30000.0f;
  const int srow = lane >> 2, sseg = (lane & 3) * 8;

  const bf16* gk0 = kbase + (size_t)(w * 32 + srow) * 64 + sseg;
  const bf16* gv0 = vtbase + (size_t)(w * 32 + srow) * 2048 + sseg;

  #define STAGE(KB, BUF)                                                     \
    {                                                                        \
      const bf16* gk = gk0 + (size_t)(KB) * 64 * 64;                         \
      load16_lds(gk,            &Ksh[BUF][0][w * 32][0]);                    \
      load16_lds(gk + 32,       &Ksh[BUF][1][w * 32][0]);                    \
      load16_lds(gk + 1024,     &Ksh[BUF][0][w * 32 + 16][0]);               \
      load16_lds(gk + 1056,     &Ksh[BUF][1][w * 32 + 16][0]);               \
      const bf16* gv = gv0 + (KB) * 64;                                      \
      load16_lds(gv,            &Vsh[BUF][0][w * 32][0]);                    \
      load16_lds(gv + 32,       &Vsh[BUF][1][w * 32][0]);                    \
      load16_lds(gv + 32768,    &Vsh[BUF][0][w * 32 + 16][0]);               \
      load16_lds(gv + 32800,    &Vsh[BUF][1][w * 32 + 16][0]);               \
    }

  if (kb_lo < kb_hi) STAGE(kb_lo, 0)

  for (int kb = kb_lo; kb < kb_hi; ++kb) {
    const int buf = (kb - kb_lo) & 1;
    __syncthreads();                       // publishes buf (drains loads)

    if (kb + 1 < kb_hi) STAGE(kb + 1, buf ^ 1)

    v8bf kf[2][4], vf[2][4];
    #pragma unroll
    for (int nf = 0; nf < 4; ++nf) {
      kf[0][nf] = *(const v8bf*)&Ksh[buf][0][nf * 16 + ln][quad * 8];
      kf[1][nf] = *(const v8bf*)&Ksh[buf][1][nf * 16 + ln][quad * 8];
      vf[0][nf] = *(const v8bf*)&Vsh[buf][0][nf * 16 + ln][quad * 8];
      vf[1][nf] = *(const v8bf*)&Vsh[buf][1][nf * 16 + ln][quad * 8];
    }

    #pragma unroll
    for (int mc = 0; mc < 2; ++mc) {
      v4f s[4];
      #pragma unroll
      for (int nf = 0; nf < 4; ++nf) s[nf] = vzero;
      #pragma unroll
      for (int ks = 0; ks < 2; ++ks)
        #pragma unroll
        for (int nf = 0; nf < 4; ++nf)
          s[nf] = MFMA16(aq[mc][ks], kf[ks][nf], s[nf]);

      if (kb == mt) {                      // causal mask (diagonal tile)
        int row = wrow + mc * 16 + quad * 4;
        #pragma unroll
        for (int nf = 0; nf < 4; ++nf) {
          int col = kb * 64 + nf * 16 + ln;
          #pragma unroll
          for (int r = 0; r < 4; ++r)
            if (col > row + r) s[nf][r] = NEG;
        }
      }

      // P = exp(S) -> per-wave LDS (C-layout), read back in A-layout
      #pragma unroll
      for (int nf = 0; nf < 4; ++nf)
        #pragma unroll
        for (int r = 0; r < 4; ++r)
          Psh[w][quad * 4 + r][nf * 16 + ln] = f2braw(__expf(s[nf][r]));
      __asm__ volatile("s_waitcnt lgkmcnt(0)" ::: "memory");

      #pragma unroll
      for (int ks = 0; ks < 2; ++ks) {
        v8bf pf = *(const v8bf*)&Psh[w][ln][ks * 32 + quad * 8];
        lacc[mc] = MFMA16(pf, vone, lacc[mc]);
        #pragma unroll
        for (int nf = 0; nf < 4; ++nf)
          o[mc][nf] = MFMA16(pf, vf[ks][nf], o[mc][nf]);
      }
    }
  }
  #undef STAGE

  // epilogue: store UN-normalized partials (zeros if chunk empty)
  bf16* op = chunk ? Op1 : Op0;
  #pragma unroll
  for (int mc = 0; mc < 2; ++mc)
    #pragma unroll
    for (int nf = 0; nf < 4; ++nf)
      #pragma unroll
      for (int r = 0; r < 4; ++r) {
        int m = b * 2048 + wrow + mc * 16 + quad * 4 + r;
        op[(size_t)m * 1024 + h * 64 + nf * 16 + ln] = f2b(o[mc][nf][r]);
      }
  if (ln == 0) {
    float* lpc = lp + chunk * 65536 + h * 4096 + b * 2048;
    #pragma unroll
    for (int mc = 0; mc < 2; ++mc)
      *(v4f*)&lpc[wrow + mc * 16 + quad * 4] = lacc[mc];
  }
}

// ---------------------------------------------------------------------------
// Combine: att = (Op0 + Op1) / (lp0 + lp1). 8 elems/thread, grid 2048x256.
// ---------------------------------------------------------------------------
__global__ __launch_bounds__(256) void combine_kernel(
    const bf16* __restrict__ Op0, const bf16* __restrict__ Op1,
    const float* __restrict__ lp, bf16* __restrict__ att)
{
  size_t base = ((size_t)blockIdx.x * 256 + threadIdx.x) * 8;
  int m = (int)(base >> 10);
  int h = ((int)base >> 6) & 15;
  float l = lp[h * 4096 + m] + lp[65536 + h * 4096 + m];
  float inv = 1.0f / l;
  v8bf a = *(const v8bf*)(Op0 + base);
  v8bf c = *(const v8bf*)(Op1 + base);
  v8bf r;
  #pragma unroll
  for (int j = 0; j < 8; ++j)
    r[j] = f2braw(((float)a[j] + (float)c[j]) * inv);
  *(v8bf*)(att + base) = r;
}

// ---------------------------------------------------------------------------
// Kernel 3: output projection + bias, fp32 out. 128x64 tiles, BK=32,
// double-buffered, one barrier per k-step, loads before fragment reads.
// ---------------------------------------------------------------------------
__global__ __launch_bounds__(256) void out_gemm_kernel(
    const bf16* __restrict__ att, const bf16* __restrict__ wot,
    const float* __restrict__ bo, float* __restrict__ out)
{
  __shared__ __align__(16) bf16 Ash[2][128][32];
  __shared__ __align__(16) bf16 Bsh[2][64][32];

  const int mt = blockIdx.x, nt = blockIdx.y;
  const int tid = threadIdx.x, w = tid >> 6, lane = tid & 63;
  const int ln = lane & 15, quad = lane >> 4;
  const int wm = w >> 1, wn = w & 1;
  const int m0 = mt * 128, n0 = nt * 64;

  const v4f vzero = {0.f, 0.f, 0.f, 0.f};
  v4f acc[4][2];
  #pragma unroll
  for (int mf = 0; mf < 4; ++mf)
    #pragma unroll
    for (int nf = 0; nf < 2; ++nf) acc[mf][nf] = vzero;

  const int srow = lane >> 2, sseg = (lane & 3) * 8;
  const bf16* ga = att + (size_t)(m0 + 32 * w + srow) * 1024 + sseg;
  const bf16* gb = wot + (size_t)(n0 + 16 * w + srow) * 1024 + sseg;

  {
    load16_lds(ga,             &Ash[0][32 * w][0]);
    load16_lds(ga + 16 * 1024, &Ash[0][32 * w + 16][0]);
    load16_lds(gb,             &Bsh[0][16 * w][0]);
  }

  for (int kt = 0; kt < 32; ++kt) {
    const int buf = kt & 1;
    __syncthreads();

    if (kt < 31) {
      const int k0 = (kt + 1) * 32, nb = buf ^ 1;
      load16_lds(ga + k0,             &Ash[nb][32 * w][0]);
      load16_lds(ga + 16 * 1024 + k0, &Ash[nb][32 * w + 16][0]);
      load16_lds(gb + k0,             &Bsh[nb][16 * w][0]);
    }

    v8bf af[4], bfv[2];
    #pragma unroll
    for (int mf = 0; mf < 4; ++mf)
      af[mf] = *(const v8bf*)&Ash[buf][wm * 64 + mf * 16 + ln][quad * 8];
    #pragma unroll
    for (int nf = 0; nf < 2; ++nf)
      bfv[nf] = *(const v8bf*)&Bsh[buf][wn * 32 + nf * 16 + ln][quad * 8];

    #pragma unroll
    for (int mf = 0; mf < 4; ++mf)
      #pragma unroll
      for (int nf = 0; nf < 2; ++nf)
        acc[mf][nf] = MFMA16(af[mf], bfv[nf], acc[mf][nf]);
  }

  #pragma unroll
  for (int nf = 0; nf < 2; ++nf) {
    int j = n0 + wn * 32 + nf * 16 + ln;
    float bias = bo[j];
    #pragma unroll
    for (int mf = 0; mf < 4; ++mf)
      #pragma unroll
      for (int r = 0; r < 4; ++r) {
        int m = m0 + wm * 64 + mf * 16 + quad * 4 + r;
        out[(size_t)m * 1024 + j] = acc[mf][nf][r] + bias;
      }
  }
}

extern "C" void kernel_launch(void* const* d_in, const int* in_sizes, int n_in,
                              void* d_out, int out_size, void* d_ws, size_t ws_size,
                              hipStream_t stream) {
  const float* x  = (const float*)d_in[0];
  const float* Wq = (const float*)d_in[1];
  const float* Wk = (const float*)d_in[2];
  const float* Wv = (const float*)d_in[3];
  const float* Wo = (const float*)d_in[4];
  const float* bo = (const float*)d_in[5];
  float* out = (float*)d_out;

  bf16* xb  = (bf16*)d_ws;
  bf16* wt  = xb + 4194304;
  bf16* wot = xb + 7340032;
  bf16* qkv = xb + 8388608;
  bf16* att = xb + 20971520;
  bf16* Op0 = xb;                          // reuse xb (dead after qkv_gemm)
  bf16* Op1 = xb + 25165824;
  float* lp = (float*)(xb + 29360128);     // [2][16][4096] fp32

  prep_kernel<<<6144, 256, 0, stream>>>(x, Wq, Wk, Wv, Wo, xb, wt, wot);
  qkv_gemm_kernel<<<dim3(32, 24), 256, 0, stream>>>(xb, wt, qkv);
  attn_kernel<<<2048, 128, 0, stream>>>(qkv, Op0, Op1, lp);
  combine_kernel<<<2048, 256, 0, stream>>>(Op0, Op1, lp, att);
  out_gemm_kernel<<<dim3(32, 16), 256, 0, stream>>>(att, wot, bo, out);
}

// Round 9
// 194.628 us; speedup vs baseline: 1.0699x; 1.0699x over previous
//
#include <hip/hip_runtime.h>
#include <hip/hip_bf16.h>

// MultiHead attention, MI355X/gfx950. fp32 in/out, bf16/f16 MFMA internals.
// B=2, T=2048, C=1024, H=16, D=64.
// Round 9: transposed-PV attention dataflow. Compute S^T = K.Q^T via
// MFMA(A=K,B=Q): C-layout row=t=quad*4+r, col=q=ln. exp'd in-register, that
// IS the B-fragment of a K=16 MFMA (n=q, k=quad*4+j) -> feed directly to
// v_mfma_f32_16x16x16f16(A=V^T-frag, B=P): NO LDS P-roundtrip, no lgkmcnt
// stalls. V stored f16; O accumulates transposed (row=d, col=q); row sums
// in-register + one shfl pair. Split-K reverted (regressed in round 8).
//
// ws layout (bf16-elem offsets):
//   xb  [4096][1024]   @ 0          (x as bf16)
//   wt  [3072][1024]   @ 4194304    (Wq/Wk/Wv fused, transposed)
//   wot [1024][1024]   @ 7340032    (Wo transposed)
//   qkv Q,K:[h][b*2048+t][d] bf16; Vt:[h][b][d][t] f16  @ 8388608
//   att [4096][1024]   @ 20971520
// total 48 MB

typedef __hip_bfloat16 bf16;
typedef __bf16 v8bf __attribute__((ext_vector_type(8)));
typedef float  v4f  __attribute__((ext_vector_type(4)));
typedef _Float16 v4h __attribute__((ext_vector_type(4)));
typedef unsigned long long u64;
typedef unsigned int u32;

#define MFMA16(a, b, c) __builtin_amdgcn_mfma_f32_16x16x32_bf16((a), (b), (c), 0, 0, 0)
#define MFMAH(a, b, c)  __builtin_amdgcn_mfma_f32_16x16x16f16((a), (b), (c), 0, 0, 0)

__device__ __forceinline__ bf16 f2b(float x) { return __float2bfloat16(x); }
__device__ __forceinline__ __bf16 f2braw(float x) {
  bf16 t = __float2bfloat16(x);
  return *reinterpret_cast<__bf16*>(&t);
}
__device__ __forceinline__ unsigned short f2bu(float x) {
  bf16 t = __float2bfloat16(x);
  return *reinterpret_cast<unsigned short*>(&t);
}
__device__ __forceinline__ unsigned short f2hu(float x) {
  _Float16 t = (_Float16)x;
  return *reinterpret_cast<unsigned short*>(&t);
}

// async global->LDS, 16B per lane; LDS dest = wave-uniform base + lane*16.
__device__ __forceinline__ void load16_lds(const void* gptr, const void* lptr) {
  __builtin_amdgcn_global_load_lds(
      (const __attribute__((address_space(1))) u32*)gptr,
      (__attribute__((address_space(3))) u32*)lptr, 16, 0, 0);
}

// ---------------------------------------------------------------------------
// Fused prep: [0,2048) cvt_x | [2048,5120) Wq/Wk/Wv transpose | [5120,6144) Wo.
// ---------------------------------------------------------------------------
__global__ __launch_bounds__(256) void prep_kernel(
    const float* __restrict__ x,
    const float* __restrict__ Wq, const float* __restrict__ Wk,
    const float* __restrict__ Wv, const float* __restrict__ Wo,
    bf16* __restrict__ xb, bf16* __restrict__ wt, bf16* __restrict__ wot)
{
  __shared__ float Lt[32][33];
  const int bid = blockIdx.x, tid = threadIdx.x;

  if (bid < 2048) {                        // x fp32 -> bf16
    size_t i = ((size_t)bid * 256 + tid) * 8;
    float4 f0 = *(const float4*)(x + i);
    float4 f1 = *(const float4*)(x + i + 4);
    v8bf v;
    v[0] = f2braw(f0.x); v[1] = f2braw(f0.y); v[2] = f2braw(f0.z); v[3] = f2braw(f0.w);
    v[4] = f2braw(f1.x); v[5] = f2braw(f1.y); v[6] = f2braw(f1.z); v[7] = f2braw(f1.w);
    *(v8bf*)(xb + i) = v;
    return;
  }
  const int tx = tid & 31, ty = tid >> 5;
  if (bid < 5120) {                        // Wq/Wk/Wv [h][1024][64] -> wt [z][64][1024]
    const int idx = bid - 2048;
    const int z = idx >> 6, rem = idx & 63;
    const int p = z >> 4, h = z & 15;
    const float* ib = ((p == 0) ? Wq : (p == 1) ? Wk : Wv) + (size_t)h * 65536;
    bf16* ob = wt + (size_t)z * 65536;
    const int j0 = (rem & 1) * 32, i0 = (rem >> 1) * 32;
    #pragma unroll
    for (int r = 0; r < 4; ++r)
      Lt[ty + 8 * r][tx] = ib[(size_t)(i0 + ty + 8 * r) * 64 + j0 + tx];
    __syncthreads();
    #pragma unroll
    for (int r = 0; r < 4; ++r)
      ob[(size_t)(j0 + ty + 8 * r) * 1024 + i0 + tx] = f2b(Lt[tx][ty + 8 * r]);
  } else {                                 // Wo [1024][1024] -> wot transposed
    const int idx = bid - 5120;
    const int j0 = (idx & 31) * 32, i0 = (idx >> 5) * 32;
    #pragma unroll
    for (int r = 0; r < 4; ++r)
      Lt[ty + 8 * r][tx] = Wo[(size_t)(i0 + ty + 8 * r) * 1024 + j0 + tx];
    __syncthreads();
    #pragma unroll
    for (int r = 0; r < 4; ++r)
      wot[(size_t)(j0 + ty + 8 * r) * 1024 + i0 + tx] = f2b(Lt[tx][ty + 8 * r]);
  }
}

// ---------------------------------------------------------------------------
// Kernel 1: fused QKV GEMM, M=4096 x N=3072, K=1024. 128x128 tile, BK=32,
// double-buffered LDS, one barrier per k-step, prefetch before frag reads.
// Epilogue: Q,K bf16 [h][m][d] (Q*1/32); V f16 transposed [h][b][d][t].
// ---------------------------------------------------------------------------
__global__ __launch_bounds__(256) void qkv_gemm_kernel(
    const bf16* __restrict__ xb, const bf16* __restrict__ wt,
    bf16* __restrict__ qkv)
{
  __shared__ __align__(16) bf16 Ash[2][128][32];
  __shared__ __align__(16) bf16 Bsh[2][128][32];

  const int mt = blockIdx.x, nt = blockIdx.y;
  const int tid = threadIdx.x, w = tid >> 6, lane = tid & 63;
  const int ln = lane & 15, quad = lane >> 4;
  const int wm = w >> 1, wn = w & 1;
  const int m0 = mt * 128, n0 = nt * 128;

  const v4f vzero = {0.f, 0.f, 0.f, 0.f};
  v4f acc[4][4];
  #pragma unroll
  for (int mf = 0; mf < 4; ++mf)
    #pragma unroll
    for (int nf = 0; nf < 4; ++nf) acc[mf][nf] = vzero;

  const int srow = lane >> 2, sseg = (lane & 3) * 8;
  const bf16* ga = xb + (size_t)(m0 + 32 * w + srow) * 1024 + sseg;
  const bf16* gb = wt + (size_t)(n0 + 32 * w + srow) * 1024 + sseg;

  {
    load16_lds(ga,             &Ash[0][32 * w][0]);
    load16_lds(ga + 16 * 1024, &Ash[0][32 * w + 16][0]);
    load16_lds(gb,             &Bsh[0][32 * w][0]);
    load16_lds(gb + 16 * 1024, &Bsh[0][32 * w + 16][0]);
  }

  for (int kt = 0; kt < 32; ++kt) {
    const int buf = kt & 1;
    __syncthreads();                       // publishes buf (drains loads)

    if (kt < 31) {                         // prefetch kt+1 (async, other buf)
      const int k0 = (kt + 1) * 32, nb = buf ^ 1;
      load16_lds(ga + k0,             &Ash[nb][32 * w][0]);
      load16_lds(ga + 16 * 1024 + k0, &Ash[nb][32 * w + 16][0]);
      load16_lds(gb + k0,             &Bsh[nb][32 * w][0]);
      load16_lds(gb + 16 * 1024 + k0, &Bsh[nb][32 * w + 16][0]);
    }

    v8bf af[4], bfv[4];
    #pragma unroll
    for (int mf = 0; mf < 4; ++mf)
      af[mf] = *(const v8bf*)&Ash[buf][wm * 64 + mf * 16 + ln][quad * 8];
    #pragma unroll
    for (int nf = 0; nf < 4; ++nf)
      bfv[nf] = *(const v8bf*)&Bsh[buf][wn * 64 + nf * 16 + ln][quad * 8];

    #pragma unroll
    for (int mf = 0; mf < 4; ++mf)
      #pragma unroll
      for (int nf = 0; nf < 4; ++nf)
        acc[mf][nf] = MFMA16(af[mf], bfv[nf], acc[mf][nf]);
  }

  const int jcol0 = n0 + wn * 64;
  const int p = jcol0 >> 10;
  const int h = (jcol0 >> 6) & 15;
  const float scale = (p == 0) ? 0.03125f : 1.0f;

  if (p < 2) {                               // Q, K: [h][m][d] bf16
    bf16* base = qkv + (size_t)p * 4194304 + (size_t)h * 262144;
    #pragma unroll
    for (int mf = 0; mf < 4; ++mf)
      #pragma unroll
      for (int nf = 0; nf < 4; ++nf) {
        int d = nf * 16 + ln;
        #pragma unroll
        for (int r = 0; r < 4; ++r) {
          int m = m0 + wm * 64 + mf * 16 + quad * 4 + r;
          base[(size_t)m * 64 + d] = f2b(acc[mf][nf][r] * scale);
        }
      }
  } else {                                   // V transposed f16: [h][b][d][t]
    _Float16* vb = (_Float16*)(qkv + (size_t)2 * 4194304 + (size_t)h * 262144);
    #pragma unroll
    for (int mf = 0; mf < 4; ++mf) {
      int mrow = m0 + wm * 64 + mf * 16 + quad * 4;
      int bi = mrow >> 11, t0 = mrow & 2047;
      #pragma unroll
      for (int nf = 0; nf < 4; ++nf) {
        int d = nf * 16 + ln;
        u64 pk = (u64)f2hu(acc[mf][nf][0]) |
                 ((u64)f2hu(acc[mf][nf][1]) << 16) |
                 ((u64)f2hu(acc[mf][nf][2]) << 32) |
                 ((u64)f2hu(acc[mf][nf][3]) << 48);
        *(u64*)(vb + (size_t)bi * 131072 + (size_t)d * 2048 + t0) = pk;
      }
    }
  }
}

// ---------------------------------------------------------------------------
// Kernel 2: causal flash attention, transposed-PV dataflow. Block = 2 waves
// x 32 Q-rows. S^T = MFMA(A=K,B=Q) -> exp in-register -> directly the
// B-frag of 16x16x16 f16 MFMA with A=V^T-frag. O transposed (row=d,col=q).
// K tiles: Ksh[buf][ks][64][32] bf16; V^T tiles: Vsh[buf][tt][64][16] f16
// (both global_load_lds-contiguous). Double-buffered, one barrier/k-tile.
// grid 1024; mt flipped on fid bit 8 for per-CU causal balance.
// ---------------------------------------------------------------------------
__global__ __launch_bounds__(128) void attn_kernel(
    const bf16* __restrict__ qkv, bf16* __restrict__ att)
{
  __shared__ __align__(16) bf16     Ksh[2][2][64][32];  // [buf][d-half][t'][32]
  __shared__ __align__(16) _Float16 Vsh[2][4][64][16];  // [buf][t-quarter][d][16]

  const int fid = blockIdx.x;                        // 0..1023
  const int mtraw = fid & 31;
  const int mt = ((fid >> 8) & 1) ? (31 - mtraw) : mtraw;
  const int grp = (fid >> 5) & 31;
  const int b = grp >> 4, h = grp & 15;
  const int row0 = mt * 64;

  const int tid = threadIdx.x, w = tid >> 6, lane = tid & 63;
  const int ln = lane & 15, quad = lane >> 4;

  const bf16* qbase = qkv + (size_t)h * 262144 + (size_t)b * 131072;
  const bf16* kbase = qbase + 4194304;
  const _Float16* vth = (const _Float16*)(qbase + 8388608);  // [d][t], stride 2048

  const int wrow = row0 + w * 32;
  // Q fragments (B-operand layout: n=q=ln, k=d=quad*8+j)
  v8bf aq[2][2];
  #pragma unroll
  for (int mc = 0; mc < 2; ++mc)
    #pragma unroll
    for (int ks = 0; ks < 2; ++ks)
      aq[mc][ks] = *(const v8bf*)(qbase +
          (size_t)(wrow + mc * 16 + ln) * 64 + ks * 32 + quad * 8);

  const v4f vzero = {0.f, 0.f, 0.f, 0.f};
  v4f o[2][4];                             // [q-tile][d-tile], C-layout: row=d,col=q
  #pragma unroll
  for (int mc = 0; mc < 2; ++mc)
    #pragma unroll
    for (int dt = 0; dt < 4; ++dt) o[mc][dt] = vzero;
  float lsum[2] = {0.f, 0.f};

  const int kb_end = mt;
  const int srow = lane >> 2, sseg = (lane & 3) * 8;

  const bf16* gk0 = kbase + (size_t)(w * 32 + srow) * 64 + sseg;
  const _Float16* gv0 = vth + (size_t)(w * 32 + (lane >> 1)) * 2048 + (lane & 1) * 8;

  #define STAGE(KB, BUF)                                                     \
    {                                                                        \
      const bf16* gk = gk0 + (size_t)(KB) * 64 * 64;                         \
      load16_lds(gk,        &Ksh[BUF][0][w * 32][0]);                        \
      load16_lds(gk + 32,   &Ksh[BUF][1][w * 32][0]);                        \
      load16_lds(gk + 1024, &Ksh[BUF][0][w * 32 + 16][0]);                   \
      load16_lds(gk + 1056, &Ksh[BUF][1][w * 32 + 16][0]);                   \
      const _Float16* gv = gv0 + (KB) * 64;                                  \
      load16_lds(gv,      &Vsh[BUF][0][w * 32][0]);                          \
      load16_lds(gv + 16, &Vsh[BUF][1][w * 32][0]);                          \
      load16_lds(gv + 32, &Vsh[BUF][2][w * 32][0]);                          \
      load16_lds(gv + 48, &Vsh[BUF][3][w * 32][0]);                          \
    }

  STAGE(0, 0)

  for (int kb = 0; kb <= kb_end; ++kb) {
    const int buf = kb & 1;
    __syncthreads();                       // publishes buf (drains loads)

    if (kb < kb_end) STAGE(kb + 1, buf ^ 1)

    // K A-frags (m=t=ln, k=d=quad*8+j) and V^T A-frags (m=d=ln, k=t=quad*4+j)
    v8bf kf[2][4];
    v4h  vf[4][4];                         // [t-quarter][d-tile]
    #pragma unroll
    for (int tt = 0; tt < 4; ++tt) {
      kf[0][tt] = *(const v8bf*)&Ksh[buf][0][tt * 16 + ln][quad * 8];
      kf[1][tt] = *(const v8bf*)&Ksh[buf][1][tt * 16 + ln][quad * 8];
      #pragma unroll
      for (int dt = 0; dt < 4; ++dt)
        vf[tt][dt] = *(const v4h*)&Vsh[buf][tt][dt * 16 + ln][quad * 4];
    }

    const bool diag = (kb == kb_end);
    #pragma unroll
    for (int mc = 0; mc < 2; ++mc) {
      // S^T tiles: D[t][q], row t=quad*4+r, col q=ln
      v4f st[4];
      #pragma unroll
      for (int tt = 0; tt < 4; ++tt) st[tt] = vzero;
      #pragma unroll
      for (int ks = 0; ks < 2; ++ks)
        #pragma unroll
        for (int tt = 0; tt < 4; ++tt)
          st[tt] = MFMA16(kf[ks][tt], aq[mc][ks], st[tt]);

      // exp (+ causal mask on diagonal tile) -> f16 B-frags, in-register
      const int q = wrow + mc * 16 + ln;
      v4h p[4];
      #pragma unroll
      for (int tt = 0; tt < 4; ++tt) {
        #pragma unroll
        for (int r = 0; r < 4; ++r) {
          int t = kb * 64 + tt * 16 + quad * 4 + r;
          float e = (diag && t > q) ? 0.f : __expf(st[tt][r]);
          lsum[mc] += e;
          p[tt][r] = (_Float16)e;
        }
      }

      // O^T += V^T . P  (16x16x16 f16, B-frag = p, zero data movement)
      #pragma unroll
      for (int dt = 0; dt < 4; ++dt)
        #pragma unroll
        for (int tt = 0; tt < 4; ++tt)
          o[mc][dt] = MFMAH(vf[tt][dt], p[tt], o[mc][dt]);
    }
  }
  #undef STAGE

  // epilogue: reduce l across quads, normalize, store att[m][h*64+d]
  #pragma unroll
  for (int mc = 0; mc < 2; ++mc) {
    float l = lsum[mc];
    l += __shfl_xor(l, 16);
    l += __shfl_xor(l, 32);
    float inv = 1.0f / l;
    const int m = b * 2048 + wrow + mc * 16 + ln;
    #pragma unroll
    for (int dt = 0; dt < 4; ++dt) {
      u64 pk = (u64)f2bu(o[mc][dt][0] * inv) |
               ((u64)f2bu(o[mc][dt][1] * inv) << 16) |
               ((u64)f2bu(o[mc][dt][2] * inv) << 32) |
               ((u64)f2bu(o[mc][dt][3] * inv) << 48);
      *(u64*)(att + (size_t)m * 1024 + h * 64 + dt * 16 + quad * 4) = pk;
    }
  }
}

// ---------------------------------------------------------------------------
// Kernel 3: output projection + bias, fp32 out. 128x64 tiles, BK=32,
// double-buffered, one barrier per k-step, prefetch before frag reads.
// ---------------------------------------------------------------------------
__global__ __launch_bounds__(256) void out_gemm_kernel(
    const bf16* __restrict__ att, const bf16* __restrict__ wot,
    const float* __restrict__ bo, float* __restrict__ out)
{
  __shared__ __align__(16) bf16 Ash[2][128][32];
  __shared__ __align__(16) bf16 Bsh[2][64][32];

  const int mt = blockIdx.x, nt = blockIdx.y;
  const int tid = threadIdx.x, w = tid >> 6, lane = tid & 63;
  const int ln = lane & 15, quad = lane >> 4;
  const int wm = w >> 1, wn = w & 1;
  const int m0 = mt * 128, n0 = nt * 64;

  const v4f vzero = {0.f, 0.f, 0.f, 0.f};
  v4f acc[4][2];
  #pragma unroll
  for (int mf = 0; mf < 4; ++mf)
    #pragma unroll
    for (int nf = 0; nf < 2; ++nf) acc[mf][nf] = vzero;

  const int srow = lane >> 2, sseg = (lane & 3) * 8;
  const bf16* ga = att + (size_t)(m0 + 32 * w + srow) * 1024 + sseg;
  const bf16* gb = wot + (size_t)(n0 + 16 * w + srow) * 1024 + sseg;

  {
    load16_lds(ga,             &Ash[0][32 * w][0]);
    load16_lds(ga + 16 * 1024, &Ash[0][32 * w + 16][0]);
    load16_lds(gb,             &Bsh[0][16 * w][0]);
  }

  for (int kt = 0; kt < 32; ++kt) {
    const int buf = kt & 1;
    __syncthreads();

    if (kt < 31) {
      const int k0 = (kt + 1) * 32, nb = buf ^ 1;
      load16_lds(ga + k0,             &Ash[nb][32 * w][0]);
      load16_lds(ga + 16 * 1024 + k0, &Ash[nb][32 * w + 16][0]);
      load16_lds(gb + k0,             &Bsh[nb][16 * w][0]);
    }

    v8bf af[4], bfv[2];
    #pragma unroll
    for (int mf = 0; mf < 4; ++mf)
      af[mf] = *(const v8bf*)&Ash[buf][wm * 64 + mf * 16 + ln][quad * 8];
    #pragma unroll
    for (int nf = 0; nf < 2; ++nf)
      bfv[nf] = *(const v8bf*)&Bsh[buf][wn * 32 + nf * 16 + ln][quad * 8];

    #pragma unroll
    for (int mf = 0; mf < 4; ++mf)
      #pragma unroll
      for (int nf = 0; nf < 2; ++nf)
        acc[mf][nf] = MFMA16(af[mf], bfv[nf], acc[mf][nf]);
  }

  #pragma unroll
  for (int nf = 0; nf < 2; ++nf) {
    int j = n0 + wn * 32 + nf * 16 + ln;
    float bias = bo[j];
    #pragma unroll
    for (int mf = 0; mf < 4; ++mf)
      #pragma unroll
      for (int r = 0; r < 4; ++r) {
        int m = m0 + wm * 64 + mf * 16 + quad * 4 + r;
        out[(size_t)m * 1024 + j] = acc[mf][nf][r] + bias;
      }
  }
}

extern "C" void kernel_launch(void* const* d_in, const int* in_sizes, int n_in,
                              void* d_out, int out_size, void* d_ws, size_t ws_size,
                              hipStream_t stream) {
  const float* x  = (const float*)d_in[0];
  const float* Wq = (const float*)d_in[1];
  const float* Wk = (const float*)d_in[2];
  const float* Wv = (const float*)d_in[3];
  const float* Wo = (const float*)d_in[4];
  const float* bo = (const float*)d_in[5];
  float* out = (float*)d_out;

  bf16* xb  = (bf16*)d_ws;
  bf16* wt  = xb + 4194304;
  bf16* wot = xb + 7340032;
  bf16* qkv = xb + 8388608;
  bf16* att = xb + 20971520;

  prep_kernel<<<6144, 256, 0, stream>>>(x, Wq, Wk, Wv, Wo, xb, wt, wot);
  qkv_gemm_kernel<<<dim3(32, 24), 256, 0, stream>>>(xb, wt, qkv);
  attn_kernel<<<1024, 128, 0, stream>>>(qkv, att);
  out_gemm_kernel<<<dim3(32, 16), 256, 0, stream>>>(att, wot, bo, out);
}